// Round 3
// baseline (6934.277 us; speedup 1.0000x reference)
//
#include <hip/hip_runtime.h>

// Seq2SeqBridge: persistent kernel, f16 MFMA, register-resident weights.
// Cross-WG sync via distributed per-WG flag words (relaxed sc1 atomics):
// producer drains vmcnt then stores its own flag; wave0 of each consumer WG
// polls all flags lane-parallel and releases its WG with one __syncthreads.

typedef _Float16 f16;
typedef _Float16 hvec8 __attribute__((ext_vector_type(8)));
typedef float fvec4 __attribute__((ext_vector_type(4)));

#define WS_FL0  0        // [2 bg][128] u32 : decoder L0 flags (v = #h0 published)
#define WS_FL1  1024     // [2 bg][128] u32 : decoder L1 flags (v = #h1 published)
#define WS_FE0  2048     // [2 bg][2 dir][64] : encoder layer0 flags
#define WS_FE1  3072     // [2 bg][2 dir][64] : encoder layer1 flags
#define WS_H0   4096
#define WS_H1   135168
#define WS_HE   266240
#define WS_DEC  397312
#define WS_Y0   17174528
// total ws use: 33,951,744 bytes

__device__ __forceinline__ fvec4 mf(hvec8 a, hvec8 b, fvec4 c) {
    return __builtin_amdgcn_mfma_f32_16x16x32_f16(a, b, c, 0, 0, 0);
}

// weights: normal cached loads (read once into registers)
__device__ __forceinline__ hvec8 ldb8(const float* p) {
    hvec8 h;
#pragma unroll
    for (int j = 0; j < 8; ++j) h[j] = (f16)p[j];
    return h;
}

// cross-WG state: relaxed agent-scope atomics (sc1, LLC-coherent)
__device__ __forceinline__ hvec8 lda8(const f16* p) {
    union { unsigned long long u[2]; hvec8 h; } x;
    x.u[0] = __hip_atomic_load((const unsigned long long*)p,     __ATOMIC_RELAXED, __HIP_MEMORY_SCOPE_AGENT);
    x.u[1] = __hip_atomic_load((const unsigned long long*)p + 1, __ATOMIC_RELAXED, __HIP_MEMORY_SCOPE_AGENT);
    return x.h;
}
__device__ __forceinline__ void st2(f16* p, float a, float b) {
    union { f16 h[2]; unsigned u; } x;
    x.h[0] = (f16)a; x.h[1] = (f16)b;
    __hip_atomic_store((unsigned*)p, x.u, __ATOMIC_RELAXED, __HIP_MEMORY_SCOPE_AGENT);
}
__device__ __forceinline__ void flag_set(unsigned* p, unsigned v) {
    __hip_atomic_store(p, v, __ATOMIC_RELAXED, __HIP_MEMORY_SCOPE_AGENT);
}
__device__ __forceinline__ unsigned flag_ld(const unsigned* p) {
    return __hip_atomic_load(p, __ATOMIC_RELAXED, __HIP_MEMORY_SCOPE_AGENT);
}
__device__ __forceinline__ unsigned long long flag_ld2(const unsigned* p) {
    return __hip_atomic_load((const unsigned long long*)p, __ATOMIC_RELAXED, __HIP_MEMORY_SCOPE_AGENT);
}
__device__ __forceinline__ void drain_vm() {
    asm volatile("s_waitcnt vmcnt(0)" ::: "memory");
}

__device__ __forceinline__ float sigf(float x) { return 1.f / (1.f + __expf(-x)); }
__device__ __forceinline__ float thf(float x) {
    x = fminf(15.f, fmaxf(-15.f, x));
    float e = __expf(2.f * x);
    return (e - 1.f) / (e + 1.f);
}

// LDS layouts: RED row stride 132 (2-way conflicts only), RED2 stride 20
#define RED(t, m, w, n)  red[(((t)*16 + (m))*132) + ((w)*16) + (n)]
#define RED2(t, m, n)    red2[(((t)*16 + (m))*20) + (n)]

__global__ void __launch_bounds__(512, 1)
seq2seq_kernel(const float* __restrict__ enc_h, const float* __restrict__ enc_c,
               const float* __restrict__ emb_W,
               const float* __restrict__ dWih0, const float* __restrict__ dWhh0,
               const float* __restrict__ dbih0, const float* __restrict__ dbhh0,
               const float* __restrict__ dWih1, const float* __restrict__ dWhh1,
               const float* __restrict__ dbih1, const float* __restrict__ dbhh1,
               const float* __restrict__ eWih, const float* __restrict__ eWhh,
               const float* __restrict__ ebih, const float* __restrict__ ebhh,
               float* __restrict__ out, char* __restrict__ ws)
{
    const int tid  = threadIdx.x;
    const int wave = tid >> 6, lane = tid & 63;
    const int wg   = blockIdx.x;
    const int bg   = wg >> 7;        // batch group (batches 16*bg .. 16*bg+15)
    const int g    = wg & 127;       // index within group
    const int dir  = g >> 6;         // encoder direction for this WG
    const int ge   = g & 63;
    const int n16  = lane & 15;
    const int kq   = (lane >> 4) * 8;

    unsigned* FL0r = (unsigned*)(ws + WS_FL0) + bg * 128;
    unsigned* FL1r = (unsigned*)(ws + WS_FL1) + bg * 128;
    unsigned* FE0a = (unsigned*)(ws + WS_FE0) + bg * 128;          // both dirs
    unsigned* FE0r = FE0a + dir * 64;
    unsigned* FE1r = (unsigned*)(ws + WS_FE1) + bg * 128 + dir * 64;

    f16* H0  = (f16*)(ws + WS_H0);    // [2 par][32][1024]
    f16* H1  = (f16*)(ws + WS_H1);    // [2 par][32][1024]
    f16* HE  = (f16*)(ws + WS_HE);    // [2 dir][2 par][32][512]
    f16* DEC = (f16*)(ws + WS_DEC);   // [256][32][1024]
    f16* Y0  = (f16*)(ws + WS_Y0);    // [256][32][1024]

    __shared__ float red[64 * 132];
    __shared__ float red2[64 * 20];
    __shared__ float cdec[2][8][16];
    __shared__ float cenc[8][16];
    __shared__ float pre0_l[32];
    __shared__ float bias1_l[32];
    __shared__ float biasE_l[32];

    // ---- wave0-only lane-parallel flag waits --------------------------------
    auto wait_dec = [&](unsigned t0, unsigned t1) {
        const unsigned* p0 = FL0r + lane * 2;
        const unsigned* p1 = FL1r + lane * 2;
        for (;;) {
            unsigned long long a = flag_ld2(p0);
            unsigned long long b = flag_ld2(p1);
            int ok = ((unsigned)a >= t0) && ((unsigned)(a >> 32) >= t0)
                  && ((unsigned)b >= t1) && ((unsigned)(b >> 32) >= t1);
            if (__all(ok)) break;
            __builtin_amdgcn_s_sleep(1);
        }
    };
    auto wait128 = [&](const unsigned* F, unsigned t) {
        const unsigned* p = F + lane * 2;
        for (;;) {
            unsigned long long a = flag_ld2(p);
            int ok = ((unsigned)a >= t) && ((unsigned)(a >> 32) >= t);
            if (__all(ok)) break;
            __builtin_amdgcn_s_sleep(1);
        }
    };
    auto wait64 = [&](const unsigned* F, unsigned t) {
        const unsigned* p = F + lane;
        for (;;) {
            int ok = (flag_ld(p) >= t);
            if (__all(ok)) break;
            __builtin_amdgcn_s_sleep(1);
        }
    };

    // ---------------- P0: decoder weight fragments -> registers -----------------
    const int u0 = g * 8;
    hvec8 bL0[2][4], bL1[2][8];
    {
        const int gate = n16 >> 2, uu = n16 & 3;
#pragma unroll
        for (int t = 0; t < 2; ++t) {
            const int r = gate * 1024 + u0 + t * 4 + uu;
#pragma unroll
            for (int s = 0; s < 4; ++s)
                bL0[t][s] = ldb8(dWhh0 + (size_t)r * 1024 + wave * 128 + s * 32 + kq);
#pragma unroll
            for (int s = 0; s < 8; ++s) {
                const int k1 = wave * 256 + s * 32;
                bL1[t][s] = (k1 < 1024)
                    ? ldb8(dWih1 + (size_t)r * 1024 + k1 + kq)
                    : ldb8(dWhh1 + (size_t)r * 1024 + (k1 - 1024) + kq);
            }
        }
    }
    // ---------------- P0: state init + pre0/biases + init flags ------------------
    if (tid < 64) {                       // wave0: layer0 state
        const int j = tid >> 4, m = tid & 15;
        const int b = bg * 16 + m, u = u0 + 2 * j;
        const float* src_c = enc_c + (size_t)b * 1024 + u;
        const float* src_h = enc_h + (size_t)b * 1024 + u;
        cdec[0][2 * j][m]     = src_c[0];
        cdec[0][2 * j + 1][m] = src_c[1];
        st2(H0 + (size_t)(32 + b) * 1024 + u, src_h[0], src_h[1]);  // parity 1
    }
    if (tid < 32) {                       // wave0 lanes 0-31: pre0 + bias1
        const int t = tid >> 4, nn = tid & 15;
        const int r = (nn >> 2) * 1024 + u0 + t * 4 + (nn & 3);
        const float4* wr4 = (const float4*)(dWih0 + (size_t)r * 512);
        const float4* x4  = (const float4*)(emb_W + 512);   // emb_W[BOS=1]
        float s = dbih0[r] + dbhh0[r];
        for (int k = 0; k < 128; ++k) {
            float4 w = wr4[k], x = x4[k];
            s += w.x * x.x + w.y * x.y + w.z * x.z + w.w * x.w;
        }
        pre0_l[tid]  = s;
        bias1_l[tid] = dbih1[r] + dbhh1[r];
    }
    if (tid < 64) {
        drain_vm();
        if (tid == 0) flag_set(FL0r + g, 1u);   // h0[-1] published
    }
    if (tid >= 64 && tid < 128) {         // wave1: layer1 state
        const int q = tid - 64, j = q >> 4, m = q & 15;
        const int b = bg * 16 + m, u = u0 + 2 * j;
        const float* src_c = enc_c + (size_t)(32 + b) * 1024 + u;
        const float* src_h = enc_h + (size_t)(32 + b) * 1024 + u;
        cdec[1][2 * j][m]     = src_c[0];
        cdec[1][2 * j + 1][m] = src_c[1];
        st2(H1 + (size_t)(32 + b) * 1024 + u, src_h[0], src_h[1]);  // parity 1
        drain_vm();
        if (tid == 64) flag_set(FL1r + g, 1u);  // h1[-1] published
    }

    // ---------------- decoder: 257 pipelined ticks -------------------------------
    // tick tau: L0 computes h0[tau] (reads h0[tau-1]); L1 computes h1[tau-1]
    // (reads h0[tau-1], h1[tau-2]).  FL0 >= tau+1 : h0[tau-1] ready (all WGs);
    // FL1 >= tau : h1[tau-2] ready.
    for (int tau = 0; tau <= 256; ++tau) {
        if (wave == 0) wait_dec((unsigned)(tau + 1), (unsigned)tau);
        __syncthreads();                 // release + RED hazard guard
        const int prd = (tau + 1) & 1;   // h0 read parity; h1 write parity
        const int pwr = tau & 1;         // h0 write parity; h1 read parity
        fvec4 acc[4];
#pragma unroll
        for (int i = 0; i < 4; ++i) acc[i] = 0;
        const int m = n16;
        if (tau < 256) {
            const f16* a0 = H0 + (size_t)(prd * 32 + bg * 16 + m) * 1024 + wave * 128 + kq;
#pragma unroll
            for (int s = 0; s < 4; ++s) {
                hvec8 a = lda8(a0 + s * 32);
                acc[0] = mf(a, bL0[0][s], acc[0]);
                acc[1] = mf(a, bL0[1][s], acc[1]);
            }
        }
        if (tau >= 1) {
            const f16* a1 = (wave < 4)
                ? H0 + (size_t)(prd * 32 + bg * 16 + m) * 1024 + wave * 256 + kq
                : H1 + (size_t)(pwr * 32 + bg * 16 + m) * 1024 + (wave - 4) * 256 + kq;
#pragma unroll
            for (int s = 0; s < 8; ++s) {
                hvec8 a = lda8(a1 + s * 32);
                acc[2] = mf(a, bL1[0][s], acc[2]);
                acc[3] = mf(a, bL1[1][s], acc[3]);
            }
        }
        {
            const int mg = lane >> 4;
#pragma unroll
            for (int t = 0; t < 4; ++t)
#pragma unroll
                for (int r = 0; r < 4; ++r)
                    RED(t, mg * 4 + r, wave, n16) = acc[t][r];
        }
        __syncthreads();
        for (int it = tid; it < 1024; it += 512) {
            const int t = it >> 8, mm = it & 15, nn = (it >> 4) & 15;
            const float* p = &RED(t, mm, 0, nn);
            RED2(t, mm, nn) = ((p[0] + p[16]) + (p[32] + p[48]))
                            + ((p[64] + p[80]) + (p[96] + p[112]));
        }
        __syncthreads();
        if (tid < 64 && tau < 256) {                       // L0 pointwise (wave 0)
            const int j = tid >> 4, m2 = tid & 15, t = j >> 1;
            float hh[2];
#pragma unroll
            for (int e = 0; e < 2; ++e) {
                const int uu = 2 * j + e, ul = uu & 3;
                const float gi = RED2(t, m2, ul)      + pre0_l[t * 16 + ul];
                const float gf = RED2(t, m2, 4 + ul)  + pre0_l[t * 16 + 4 + ul];
                const float gg = RED2(t, m2, 8 + ul)  + pre0_l[t * 16 + 8 + ul];
                const float go = RED2(t, m2, 12 + ul) + pre0_l[t * 16 + 12 + ul];
                float c = cdec[0][uu][m2];
                c = sigf(gf) * c + sigf(gi) * thf(gg);
                hh[e] = sigf(go) * thf(c);
                cdec[0][uu][m2] = c;
            }
            st2(H0 + (size_t)(pwr * 32 + bg * 16 + m2) * 1024 + u0 + 2 * j, hh[0], hh[1]);
            drain_vm();
            if (tid == 0) flag_set(FL0r + g, (unsigned)(tau + 2));   // h0[tau]
        }
        if (tid >= 64 && tid < 128 && tau >= 1) {          // L1 pointwise (wave 1)
            const int q = tid - 64;
            const int j = q >> 4, m2 = q & 15, t = j >> 1;
            float hh[2];
#pragma unroll
            for (int e = 0; e < 2; ++e) {
                const int uu = 2 * j + e, ul = uu & 3;
                const float gi = RED2(2 + t, m2, ul)      + bias1_l[t * 16 + ul];
                const float gf = RED2(2 + t, m2, 4 + ul)  + bias1_l[t * 16 + 4 + ul];
                const float gg = RED2(2 + t, m2, 8 + ul)  + bias1_l[t * 16 + 8 + ul];
                const float go = RED2(2 + t, m2, 12 + ul) + bias1_l[t * 16 + 12 + ul];
                float c = cdec[1][uu][m2];
                c = sigf(gf) * c + sigf(gi) * thf(gg);
                hh[e] = sigf(go) * thf(c);
                cdec[1][uu][m2] = c;
            }
            const int b = bg * 16 + m2, u = u0 + 2 * j;
            st2(H1 + (size_t)(prd * 32 + b) * 1024 + u, hh[0], hh[1]);
            st2(DEC + ((size_t)(tau - 1) * 32 + b) * 1024 + u, hh[0], hh[1]);
            drain_vm();
            if (tid == 64) flag_set(FL1r + g, (unsigned)(tau + 1));  // h1[tau-1]
        }
    }

    // ---------------- encoder: 2 layers x 256 ticks, fwd/bwd in own domains ------
    const int ue0 = ge * 8;
    for (int l = 0; l < 2; ++l) {
        unsigned* FEcur = l ? FE1r : FE0r;
        hvec8 bE[2][6];
        {
            const int gate = n16 >> 2, uu = n16 & 3;
            const float* Wih = eWih + (size_t)(l * 2 + dir) * 2048 * 1024;
            const float* Whh = eWhh + (size_t)(l * 2 + dir) * 2048 * 512;
#pragma unroll
            for (int t = 0; t < 2; ++t) {
                const int r = gate * 512 + ue0 + t * 4 + uu;
#pragma unroll
                for (int s = 0; s < 6; ++s) {
                    const int kb = wave * 192 + s * 32;
                    bE[t][s] = (kb < 1024)
                        ? ldb8(Wih + (size_t)r * 1024 + kb + kq)
                        : ldb8(Whh + (size_t)r * 512 + (kb - 1024) + kq);
                }
            }
        }
        if (tid < 32) {
            const int t = tid >> 4, nn = tid & 15;
            const int r = (nn >> 2) * 512 + ue0 + t * 4 + (nn & 3);
            biasE_l[tid] = ebih[(size_t)(l * 2 + dir) * 2048 + r]
                         + ebhh[(size_t)(l * 2 + dir) * 2048 + r];
        }
        if (tid < 64) {
            const int j = tid >> 4, m = tid & 15;
            cenc[2 * j][m] = 0.f;
            cenc[2 * j + 1][m] = 0.f;
            st2(HE + (size_t)((dir * 2 + 1) * 32 + bg * 16 + m) * 512 + ue0 + 2 * j, 0.f, 0.f);
            drain_vm();
            if (tid == 0) flag_set(FEcur + ge, 1u);         // hE[-1] published
        }
        if (wave == 0) {
            if (l == 0) wait_dec(257u, 257u);   // DEC fully published
            else        wait128(FE0a, 257u);    // Y0 (both dirs) fully published
        }
        const f16* yprev = (l == 0) ? DEC : Y0;
        for (int tau = 0; tau < 256; ++tau) {
            if (wave == 0) wait64(FEcur, (unsigned)(tau + 1));
            __syncthreads();
            const int t = dir ? (255 - tau) : tau;
            const int prd = (tau + 1) & 1, pwr = tau & 1;
            fvec4 acc2[2];
            acc2[0] = 0; acc2[1] = 0;
            const int m = n16, b = bg * 16 + m;
#pragma unroll
            for (int s = 0; s < 6; ++s) {
                const int kb = wave * 192 + s * 32;
                const f16* p = (kb < 1024)
                    ? yprev + ((size_t)t * 32 + b) * 1024 + kb + kq
                    : HE + (size_t)((dir * 2 + prd) * 32 + b) * 512 + (kb - 1024) + kq;
                hvec8 a = lda8(p);
                acc2[0] = mf(a, bE[0][s], acc2[0]);
                acc2[1] = mf(a, bE[1][s], acc2[1]);
            }
            const int mg = lane >> 4;
#pragma unroll
            for (int tt = 0; tt < 2; ++tt)
#pragma unroll
                for (int r = 0; r < 4; ++r)
                    RED(tt, mg * 4 + r, wave, n16) = acc2[tt][r];
            __syncthreads();
            {
                const int t2 = tid >> 8, mm = tid & 15, nn = (tid >> 4) & 15;
                const float* p = &RED(t2, mm, 0, nn);
                RED2(t2, mm, nn) = ((p[0] + p[16]) + (p[32] + p[48]))
                                 + ((p[64] + p[80]) + (p[96] + p[112]));
            }
            __syncthreads();
            if (tid < 64) {
                const int j = tid >> 4, m2 = tid & 15, tt = j >> 1;
                float hh[2], cc[2];
#pragma unroll
                for (int e = 0; e < 2; ++e) {
                    const int uu = 2 * j + e, ul = uu & 3;
                    const float gi = RED2(tt, m2, ul)      + biasE_l[tt * 16 + ul];
                    const float gf = RED2(tt, m2, 4 + ul)  + biasE_l[tt * 16 + 4 + ul];
                    const float gg = RED2(tt, m2, 8 + ul)  + biasE_l[tt * 16 + 8 + ul];
                    const float go = RED2(tt, m2, 12 + ul) + biasE_l[tt * 16 + 12 + ul];
                    float c = cenc[uu][m2];
                    c = sigf(gf) * c + sigf(gi) * thf(gg);
                    hh[e] = sigf(go) * thf(c);
                    cc[e] = c;
                    cenc[uu][m2] = c;
                }
                const int b2 = bg * 16 + m2, u = ue0 + 2 * j;
                st2(HE + (size_t)((dir * 2 + pwr) * 32 + b2) * 512 + u, hh[0], hh[1]);
                if (l == 0) {
                    st2(Y0 + ((size_t)t * 32 + b2) * 1024 + dir * 512 + u, hh[0], hh[1]);
                } else {
                    float* o = out + ((size_t)b2 * 256 + t) * 1024 + dir * 512 + u;
                    o[0] = hh[0]; o[1] = hh[1];
                    if (tau == 255) {   // final states -> dec_h / dec_c
                        const int col = dir * 512 + u;
                        float* oh = out + 8388608 + (size_t)b2 * 1024 + col;
                        float* oc = out + 8454144 + (size_t)b2 * 1024 + col;
                        oh[0] = hh[0]; oh[1] = hh[1];
                        oh[32768] = hh[0]; oh[32769] = hh[1];
                        oc[0] = cc[0]; oc[1] = cc[1];
                        oc[32768] = cc[0]; oc[32769] = cc[1];
                    }
                }
                drain_vm();
                if (tid == 0) flag_set(FEcur + ge, (unsigned)(tau + 2));  // hE[tau]
            }
        }
    }
}

extern "C" void kernel_launch(void* const* d_in, const int* in_sizes, int n_in,
                              void* d_out, int out_size, void* d_ws, size_t ws_size,
                              hipStream_t stream) {
    (void)in_sizes; (void)n_in; (void)out_size; (void)ws_size;
    const float* enc_h = (const float*)d_in[1];
    const float* enc_c = (const float*)d_in[2];
    const float* emb_W = (const float*)d_in[4];
    const float* dWih0 = (const float*)d_in[5];
    const float* dWhh0 = (const float*)d_in[6];
    const float* dbih0 = (const float*)d_in[7];
    const float* dbhh0 = (const float*)d_in[8];
    const float* dWih1 = (const float*)d_in[9];
    const float* dWhh1 = (const float*)d_in[10];
    const float* dbih1 = (const float*)d_in[11];
    const float* dbhh1 = (const float*)d_in[12];
    const float* eWih  = (const float*)d_in[13];
    const float* eWhh  = (const float*)d_in[14];
    const float* ebih  = (const float*)d_in[15];
    const float* ebhh  = (const float*)d_in[16];
    float* outp = (float*)d_out;
    char* ws = (char*)d_ws;

    // zero the flag arrays (ws is re-poisoned before every launch)
    hipMemsetAsync(d_ws, 0, 4096, stream);

    void* args[] = {&enc_h, &enc_c, &emb_W, &dWih0, &dWhh0, &dbih0, &dbhh0,
                    &dWih1, &dWhh1, &dbih1, &dbhh1, &eWih, &eWhh, &ebih, &ebhh,
                    &outp, &ws};
    hipLaunchCooperativeKernel((const void*)seq2seq_kernel, dim3(256), dim3(512),
                               args, 0, stream);
}

// Round 4
// 6351.292 us; speedup vs baseline: 1.0918x; 1.0918x over previous
//
#include <hip/hip_runtime.h>

// Seq2SeqBridge: persistent kernel, f16 MFMA, register-resident weights.
// NO per-tick barriers/flags: cross-WG handoff via poison-polling dataflow.
// ws is poisoned to 0xAA by the harness before every launch; a dword is
// "published" iff != 0xAAAAAAAA. Consumers poll-load their own MFMA A-frags
// (sc1/LLC) until fresh; the poll IS the data load. Ring slots (h-state) are
// re-poisoned by producers two slots ahead (safe by the lag invariant:
// a WG at tick T implies all polls of tick T-1 completed device-wide).

typedef _Float16 f16;
typedef _Float16 hvec8 __attribute__((ext_vector_type(8)));
typedef float fvec4 __attribute__((ext_vector_type(4)));

#define POISON 0xAAAAAAAAu
// ws layout (bytes):
//  CTRL @0        : one u32 barrier counter (zeroed via hipMemsetAsync)
//  RNG  @4096     : decoder h0 ring [2bg][4 slot][16][1024] f16 (256KB)
//                   reused by encoder as hE ring [2bg][2dir][4][16][512] f16
//  DECX @266240   : [2bg][257][16][1024] f16 ; DECX[bg][i] = h1[i-1]
//  Y0   @17108992 : [2bg][256][16][1024] f16
//  end 33886208
#define WS_RNG  4096
#define WS_DECX 266240
#define WS_Y0   17108992

__device__ __forceinline__ fvec4 mf(hvec8 a, hvec8 b, fvec4 c) {
    return __builtin_amdgcn_mfma_f32_16x16x32_f16(a, b, c, 0, 0, 0);
}
__device__ __forceinline__ hvec8 ldb8(const float* p) {
    hvec8 h;
#pragma unroll
    for (int j = 0; j < 8; ++j) h[j] = (f16)p[j];
    return h;
}

union GU { unsigned long long q[2]; unsigned w[4]; hvec8 h; };

__device__ __forceinline__ void ldg16(GU& g, const f16* p) {
    g.q[0] = __hip_atomic_load((const unsigned long long*)p,     __ATOMIC_RELAXED, __HIP_MEMORY_SCOPE_AGENT);
    g.q[1] = __hip_atomic_load((const unsigned long long*)p + 1, __ATOMIC_RELAXED, __HIP_MEMORY_SCOPE_AGENT);
}
__device__ __forceinline__ int okg(const GU& g) {
    return (g.w[0] != POISON) & (g.w[1] != POISON) & (g.w[2] != POISON) & (g.w[3] != POISON);
}
__device__ __forceinline__ unsigned pack2(float a, float b) {
    union { f16 h[2]; unsigned u; } x;
    x.h[0] = (f16)a; x.h[1] = (f16)b;
    if (x.u == POISON) x.u ^= 1u;   // 1-ulp nudge, never emit the poison pattern
    return x.u;
}
__device__ __forceinline__ void stw(f16* p, unsigned v) {
    __hip_atomic_store((unsigned*)p, v, __ATOMIC_RELAXED, __HIP_MEMORY_SCOPE_AGENT);
}
__device__ __forceinline__ float sigf(float x) { return 1.f / (1.f + __expf(-x)); }
__device__ __forceinline__ float thf(float x) {
    x = fminf(15.f, fmaxf(-15.f, x));
    float e = __expf(2.f * x);
    return (e - 1.f) / (e + 1.f);
}

#define RED(t, m, w_, n)  red[(((t)*16 + (m))*132) + ((w_)*16) + (n)]
#define RED2(t, m, n)     red2[(((t)*16 + (m))*20) + (n)]

__global__ void __launch_bounds__(512, 1)
seq2seq_kernel(const float* __restrict__ enc_h, const float* __restrict__ enc_c,
               const float* __restrict__ emb_W,
               const float* __restrict__ dWih0, const float* __restrict__ dWhh0,
               const float* __restrict__ dbih0, const float* __restrict__ dbhh0,
               const float* __restrict__ dWih1, const float* __restrict__ dWhh1,
               const float* __restrict__ dbih1, const float* __restrict__ dbhh1,
               const float* __restrict__ eWih, const float* __restrict__ eWhh,
               const float* __restrict__ ebih, const float* __restrict__ ebhh,
               float* __restrict__ out, char* __restrict__ ws)
{
    const int tid  = threadIdx.x;
    const int wave = tid >> 6, lane = tid & 63;
    const int wg   = blockIdx.x;
    const int bg   = wg >> 7;        // batch group (batches 16*bg .. 16*bg+15)
    const int g    = wg & 127;
    const int dir  = g >> 6;         // encoder direction
    const int ge   = g & 63;
    const int n16  = lane & 15;
    const int kq   = (lane >> 4) * 8;
    const int u0   = g * 8;          // decoder units (of 1024)
    const int ue0  = ge * 8;         // encoder units (of 512)

    unsigned* ctr = (unsigned*)ws;
    f16* RNG  = (f16*)(ws + WS_RNG);
    f16* DECX = (f16*)(ws + WS_DECX);
    f16* Y0   = (f16*)(ws + WS_Y0);

    __shared__ float red[64 * 132];
    __shared__ float red2[64 * 20];
    __shared__ float cdec[2][8][16];
    __shared__ float cenc[8][16];
    __shared__ float pre0_l[32];
    __shared__ float bias1_l[32];
    __shared__ float biasE_l[32];

    auto gbar = [&](unsigned tgt) {   // one-time phase barriers only
        __syncthreads();
        if (tid == 0) {
            __hip_atomic_fetch_add(ctr, 1u, __ATOMIC_RELAXED, __HIP_MEMORY_SCOPE_AGENT);
            while (__hip_atomic_load(ctr, __ATOMIC_RELAXED, __HIP_MEMORY_SCOPE_AGENT) < tgt)
                __builtin_amdgcn_s_sleep(2);
        }
        __syncthreads();
    };

    // ---------------- decoder weight fragments -> registers ---------------------
    // bL1 K-mapping: s<4 -> Wih1 (h0 input) cols wave*128+s*32 ; s>=4 -> Whh1
    // (h1 input) cols wave*128+(s-4)*32.  A-frags for the h0 half are REUSED
    // from L0's poll loads (same slice).
    hvec8 bL0[2][4], bL1[2][8];
    {
        const int gate = n16 >> 2, uu = n16 & 3;
#pragma unroll
        for (int t = 0; t < 2; ++t) {
            const int r = gate * 1024 + u0 + t * 4 + uu;
#pragma unroll
            for (int s = 0; s < 4; ++s) {
                bL0[t][s]     = ldb8(dWhh0 + (size_t)r * 1024 + wave * 128 + s * 32 + kq);
                bL1[t][s]     = ldb8(dWih1 + (size_t)r * 1024 + wave * 128 + s * 32 + kq);
                bL1[t][4 + s] = ldb8(dWhh1 + (size_t)r * 1024 + wave * 128 + s * 32 + kq);
            }
        }
    }

    // ---------------- poison own write-regions (pre-barrier) ---------------------
    // RNG decoder view slots 0..2 (slot 3 gets the init write below)
    for (int i = tid; i < 192; i += 512) {
        const int s = i >> 6, b2 = (i >> 2) & 15, j = i & 3;
        stw(RNG + ((size_t)((bg * 4 + s) * 16 + b2)) * 1024 + u0 + 2 * j, POISON);
    }
    // DECX t=1..256 (t=0 gets the init write)
    for (int i = tid; i < 256 * 64; i += 512) {
        const int t = 1 + (i >> 6), b2 = (i >> 2) & 15, j = i & 3;
        stw(DECX + ((size_t)(bg * 257 + t) * 16 + b2) * 1024 + u0 + 2 * j, POISON);
    }
    // Y0 all t (encoder-role columns)
    for (int i = tid; i < 256 * 64; i += 512) {
        const int t = i >> 6, b2 = (i >> 2) & 15, j = i & 3;
        stw(Y0 + ((size_t)(bg * 256 + t) * 16 + b2) * 1024 + dir * 512 + ue0 + 2 * j, POISON);
    }

    // ---------------- init state + pre0/biases -----------------------------------
    if (tid < 64) {                       // h0[-1] -> RNG slot 3 ; c0
        const int j = tid >> 4, m = tid & 15;
        const int b = bg * 16 + m, u = u0 + 2 * j;
        const float* pc = enc_c + (size_t)b * 1024 + u;
        const float* ph = enc_h + (size_t)b * 1024 + u;
        cdec[0][2 * j][m] = pc[0]; cdec[0][2 * j + 1][m] = pc[1];
        stw(RNG + ((size_t)((bg * 4 + 3) * 16 + m)) * 1024 + u, pack2(ph[0], ph[1]));
    }
    if (tid >= 64 && tid < 128) {         // h1[-1] -> DECX[0] ; c1
        const int q = tid - 64, j = q >> 4, m = q & 15;
        const int b = bg * 16 + m, u = u0 + 2 * j;
        const float* pc = enc_c + (size_t)(32 + b) * 1024 + u;
        const float* ph = enc_h + (size_t)(32 + b) * 1024 + u;
        cdec[1][2 * j][m] = pc[0]; cdec[1][2 * j + 1][m] = pc[1];
        stw(DECX + ((size_t)(bg * 257) * 16 + m) * 1024 + u, pack2(ph[0], ph[1]));
    }
    if (tid < 32) {                       // pre0 = x0@Wih0^T + biases ; bias1
        const int t = tid >> 4, nn = tid & 15;
        const int r = (nn >> 2) * 1024 + u0 + t * 4 + (nn & 3);
        const float4* wr4 = (const float4*)(dWih0 + (size_t)r * 512);
        const float4* x4  = (const float4*)(emb_W + 512);   // emb_W[BOS=1]
        float s = dbih0[r] + dbhh0[r];
        for (int k = 0; k < 128; ++k) {
            float4 w = wr4[k], x = x4[k];
            s += w.x * x.x + w.y * x.y + w.z * x.z + w.w * x.w;
        }
        pre0_l[tid]  = s;
        bias1_l[tid] = dbih1[r] + dbhh1[r];
    }
    gbar(256);   // B0: poisons + inits visible everywhere

    // ---------------- decoder: 257 pipelined ticks (no barriers) ----------------
    for (int tau = 0; tau <= 256; ++tau) {
        const int wsl = tau & 3, psl = (tau + 2) & 3, rsl = (tau + 3) & 3;
        // ---- poll + load A-fragments (the poll IS the load) ----
        GU a0[4], a1[4];
        {
            const f16* p0 = RNG + ((size_t)((bg * 4 + rsl) * 16 + n16)) * 1024 + wave * 128 + kq;
            const f16* p1 = DECX + ((size_t)(bg * 257 + (tau > 0 ? tau - 1 : 0)) * 16 + n16) * 1024 + wave * 128 + kq;
            unsigned pend = (tau >= 1) ? 0xFFu : 0x0Fu;
            for (;;) {
#pragma unroll
                for (int s = 0; s < 4; ++s) if (pend & (1u << s))  ldg16(a0[s], p0 + s * 32);
#pragma unroll
                for (int s = 0; s < 4; ++s) if (pend & (16u << s)) ldg16(a1[s], p1 + s * 32);
                unsigned np = 0;
#pragma unroll
                for (int s = 0; s < 4; ++s) if ((pend & (1u << s))  && !okg(a0[s])) np |= 1u << s;
#pragma unroll
                for (int s = 0; s < 4; ++s) if ((pend & (16u << s)) && !okg(a1[s])) np |= 16u << s;
                pend = np;
                if (__all(np == 0)) break;
                __builtin_amdgcn_s_sleep(1);
            }
        }
        // ---- MFMA ----
        fvec4 acc[4];
#pragma unroll
        for (int i = 0; i < 4; ++i) acc[i] = 0;
        if (tau < 256) {
#pragma unroll
            for (int s = 0; s < 4; ++s) {
                acc[0] = mf(a0[s].h, bL0[0][s], acc[0]);
                acc[1] = mf(a0[s].h, bL0[1][s], acc[1]);
            }
        }
        if (tau >= 1) {
#pragma unroll
            for (int s = 0; s < 4; ++s) {
                acc[2] = mf(a0[s].h, bL1[0][s], acc[2]);
                acc[3] = mf(a0[s].h, bL1[1][s], acc[3]);
            }
#pragma unroll
            for (int s = 0; s < 4; ++s) {
                acc[2] = mf(a1[s].h, bL1[0][4 + s], acc[2]);
                acc[3] = mf(a1[s].h, bL1[1][4 + s], acc[3]);
            }
        }
        // ---- cross-wave K reduction in LDS ----
        {
            const int mg = lane >> 4;
#pragma unroll
            for (int t = 0; t < 4; ++t)
#pragma unroll
                for (int r = 0; r < 4; ++r)
                    RED(t, mg * 4 + r, wave, n16) = acc[t][r];
        }
        __syncthreads();
        for (int it = tid; it < 1024; it += 512) {
            const int t = it >> 8, mm = it & 15, nn = (it >> 4) & 15;
            const float* p = &RED(t, mm, 0, nn);
            RED2(t, mm, nn) = ((p[0] + p[16]) + (p[32] + p[48]))
                            + ((p[64] + p[80]) + (p[96] + p[112]));
        }
        __syncthreads();
        // ---- pointwise + publish ----
        if (tid < 64 && tau < 256) {                       // L0 (wave 0)
            const int j = tid >> 4, m2 = tid & 15, t = j >> 1;
            float hh[2];
#pragma unroll
            for (int e = 0; e < 2; ++e) {
                const int uu = 2 * j + e, ul = uu & 3;
                const float gi = RED2(t, m2, ul)      + pre0_l[t * 16 + ul];
                const float gf = RED2(t, m2, 4 + ul)  + pre0_l[t * 16 + 4 + ul];
                const float gg = RED2(t, m2, 8 + ul)  + pre0_l[t * 16 + 8 + ul];
                const float go = RED2(t, m2, 12 + ul) + pre0_l[t * 16 + 12 + ul];
                float c = cdec[0][uu][m2];
                c = sigf(gf) * c + sigf(gi) * thf(gg);
                hh[e] = sigf(go) * thf(c);
                cdec[0][uu][m2] = c;
            }
            stw(RNG + ((size_t)((bg * 4 + wsl) * 16 + m2)) * 1024 + u0 + 2 * j, pack2(hh[0], hh[1]));
            stw(RNG + ((size_t)((bg * 4 + psl) * 16 + m2)) * 1024 + u0 + 2 * j, POISON);
        }
        if (tid >= 64 && tid < 128 && tau >= 1) {          // L1 (wave 1)
            const int q = tid - 64, j = q >> 4, m2 = q & 15, t = j >> 1;
            float hh[2];
#pragma unroll
            for (int e = 0; e < 2; ++e) {
                const int uu = 2 * j + e, ul = uu & 3;
                const float gi = RED2(2 + t, m2, ul)      + bias1_l[t * 16 + ul];
                const float gf = RED2(2 + t, m2, 4 + ul)  + bias1_l[t * 16 + 4 + ul];
                const float gg = RED2(2 + t, m2, 8 + ul)  + bias1_l[t * 16 + 8 + ul];
                const float go = RED2(2 + t, m2, 12 + ul) + bias1_l[t * 16 + 12 + ul];
                float c = cdec[1][uu][m2];
                c = sigf(gf) * c + sigf(gi) * thf(gg);
                hh[e] = sigf(go) * thf(c);
                cdec[1][uu][m2] = c;
            }
            // h1[tau-1]: publish + sequence in one store
            stw(DECX + ((size_t)(bg * 257 + tau) * 16 + m2) * 1024 + u0 + 2 * j, pack2(hh[0], hh[1]));
        }
    }

    // ---------------- encoder: 2 layers x 256 ticks ------------------------------
    gbar(512);   // B1a: all decoder reads of RNG done before re-poison
    for (int l = 0; l < 2; ++l) {
        if (l == 1) gbar(1024);  // B2a: all L0 reads of RNG(enc) done
        // re-poison enc ring slots 0..2 ; zero slot 3 ; cenc=0
        for (int i = tid; i < 192; i += 512) {
            const int s = i >> 6, b2 = (i >> 2) & 15, j = i & 3;
            stw(RNG + ((size_t)(((bg * 2 + dir) * 4 + s) * 16 + b2)) * 512 + ue0 + 2 * j, POISON);
        }
        if (tid < 64) {
            const int j = tid >> 4, m = tid & 15;
            cenc[2 * j][m] = 0.f; cenc[2 * j + 1][m] = 0.f;
            stw(RNG + ((size_t)(((bg * 2 + dir) * 4 + 3) * 16 + m)) * 512 + ue0 + 2 * j, 0u);
        }
        hvec8 bE[2][6];
        {
            const int gate = n16 >> 2, uu = n16 & 3;
            const float* Wih = eWih + (size_t)(l * 2 + dir) * 2048 * 1024;
            const float* Whh = eWhh + (size_t)(l * 2 + dir) * 2048 * 512;
#pragma unroll
            for (int t = 0; t < 2; ++t) {
                const int r = gate * 512 + ue0 + t * 4 + uu;
#pragma unroll
                for (int s = 0; s < 4; ++s)
                    bE[t][s] = ldb8(Wih + (size_t)r * 1024 + wave * 128 + s * 32 + kq);
#pragma unroll
                for (int s = 0; s < 2; ++s)
                    bE[t][4 + s] = ldb8(Whh + (size_t)r * 512 + wave * 64 + s * 32 + kq);
            }
        }
        if (tid < 32) {
            const int t = tid >> 4, nn = tid & 15;
            const int r = (nn >> 2) * 512 + ue0 + t * 4 + (nn & 3);
            biasE_l[tid] = ebih[(size_t)(l * 2 + dir) * 2048 + r]
                         + ebhh[(size_t)(l * 2 + dir) * 2048 + r];
        }
        gbar(l ? 1280 : 768);   // B1b/B2b: ring re-poison + init visible

        for (int tau = 0; tau < 256; ++tau) {
            const int t = dir ? (255 - tau) : tau;
            const int wsl = tau & 3, psl = (tau + 2) & 3, rsl = (tau + 3) & 3;
            GU ay[4], ah[2];
            {
                const f16* py = (l == 0)
                    ? DECX + ((size_t)(bg * 257 + t + 1) * 16 + n16) * 1024 + wave * 128 + kq
                    : Y0   + ((size_t)(bg * 256 + t) * 16 + n16) * 1024 + wave * 128 + kq;
                const f16* ph = RNG + ((size_t)(((bg * 2 + dir) * 4 + rsl) * 16 + n16)) * 512 + wave * 64 + kq;
                unsigned pend = 0x3Fu;
                for (;;) {
#pragma unroll
                    for (int s = 0; s < 4; ++s) if (pend & (1u << s))  ldg16(ay[s], py + s * 32);
#pragma unroll
                    for (int s = 0; s < 2; ++s) if (pend & (16u << s)) ldg16(ah[s], ph + s * 32);
                    unsigned np = 0;
#pragma unroll
                    for (int s = 0; s < 4; ++s) if ((pend & (1u << s))  && !okg(ay[s])) np |= 1u << s;
#pragma unroll
                    for (int s = 0; s < 2; ++s) if ((pend & (16u << s)) && !okg(ah[s])) np |= 16u << s;
                    pend = np;
                    if (__all(np == 0)) break;
                    __builtin_amdgcn_s_sleep(1);
                }
            }
            fvec4 acc2[2];
            acc2[0] = 0; acc2[1] = 0;
#pragma unroll
            for (int s = 0; s < 4; ++s) {
                acc2[0] = mf(ay[s].h, bE[0][s], acc2[0]);
                acc2[1] = mf(ay[s].h, bE[1][s], acc2[1]);
            }
#pragma unroll
            for (int s = 0; s < 2; ++s) {
                acc2[0] = mf(ah[s].h, bE[0][4 + s], acc2[0]);
                acc2[1] = mf(ah[s].h, bE[1][4 + s], acc2[1]);
            }
            {
                const int mg = lane >> 4;
#pragma unroll
                for (int tt = 0; tt < 2; ++tt)
#pragma unroll
                    for (int r = 0; r < 4; ++r)
                        RED(tt, mg * 4 + r, wave, n16) = acc2[tt][r];
            }
            __syncthreads();
            {
                const int t2 = tid >> 8, mm = tid & 15, nn = (tid >> 4) & 15;
                const float* p = &RED(t2, mm, 0, nn);
                RED2(t2, mm, nn) = ((p[0] + p[16]) + (p[32] + p[48]))
                                 + ((p[64] + p[80]) + (p[96] + p[112]));
            }
            __syncthreads();
            if (tid < 64) {
                const int j = tid >> 4, m2 = tid & 15, tt = j >> 1;
                float hh[2], cc[2];
#pragma unroll
                for (int e = 0; e < 2; ++e) {
                    const int uu = 2 * j + e, ul = uu & 3;
                    const float gi = RED2(tt, m2, ul)      + biasE_l[tt * 16 + ul];
                    const float gf = RED2(tt, m2, 4 + ul)  + biasE_l[tt * 16 + 4 + ul];
                    const float gg = RED2(tt, m2, 8 + ul)  + biasE_l[tt * 16 + 8 + ul];
                    const float go = RED2(tt, m2, 12 + ul) + biasE_l[tt * 16 + 12 + ul];
                    float c = cenc[uu][m2];
                    c = sigf(gf) * c + sigf(gi) * thf(gg);
                    hh[e] = sigf(go) * thf(c);
                    cc[e] = c;
                    cenc[uu][m2] = c;
                }
                const int u = ue0 + 2 * j;
                stw(RNG + ((size_t)(((bg * 2 + dir) * 4 + wsl) * 16 + m2)) * 512 + u, pack2(hh[0], hh[1]));
                stw(RNG + ((size_t)(((bg * 2 + dir) * 4 + psl) * 16 + m2)) * 512 + u, POISON);
                const int b2 = bg * 16 + m2;
                if (l == 0) {
                    stw(Y0 + ((size_t)(bg * 256 + t) * 16 + m2) * 1024 + dir * 512 + u, pack2(hh[0], hh[1]));
                } else {
                    float* o = out + ((size_t)b2 * 256 + t) * 1024 + dir * 512 + u;
                    o[0] = hh[0]; o[1] = hh[1];
                    if (tau == 255) {   // final states -> dec_h / dec_c
                        const int col = dir * 512 + u;
                        float* oh = out + 8388608 + (size_t)b2 * 1024 + col;
                        float* oc = out + 8454144 + (size_t)b2 * 1024 + col;
                        oh[0] = hh[0]; oh[1] = hh[1];
                        oh[32768] = hh[0]; oh[32769] = hh[1];
                        oc[0] = cc[0]; oc[1] = cc[1];
                        oc[32768] = cc[0]; oc[32769] = cc[1];
                    }
                }
            }
        }
    }
}

extern "C" void kernel_launch(void* const* d_in, const int* in_sizes, int n_in,
                              void* d_out, int out_size, void* d_ws, size_t ws_size,
                              hipStream_t stream) {
    (void)in_sizes; (void)n_in; (void)out_size; (void)ws_size;
    const float* enc_h = (const float*)d_in[1];
    const float* enc_c = (const float*)d_in[2];
    const float* emb_W = (const float*)d_in[4];
    const float* dWih0 = (const float*)d_in[5];
    const float* dWhh0 = (const float*)d_in[6];
    const float* dbih0 = (const float*)d_in[7];
    const float* dbhh0 = (const float*)d_in[8];
    const float* dWih1 = (const float*)d_in[9];
    const float* dWhh1 = (const float*)d_in[10];
    const float* dbih1 = (const float*)d_in[11];
    const float* dbhh1 = (const float*)d_in[12];
    const float* eWih  = (const float*)d_in[13];
    const float* eWhh  = (const float*)d_in[14];
    const float* ebih  = (const float*)d_in[15];
    const float* ebhh  = (const float*)d_in[16];
    float* outp = (float*)d_out;
    char* ws = (char*)d_ws;

    // zero ONLY the phase-barrier counter; everything else relies on 0xAA poison
    hipMemsetAsync(d_ws, 0, 256, stream);

    void* args[] = {&enc_h, &enc_c, &emb_W, &dWih0, &dWhh0, &dbih0, &dbhh0,
                    &dWih1, &dWhh1, &dbih1, &dbhh1, &eWih, &eWhh, &ebih, &ebhh,
                    &outp, &ws};
    hipLaunchCooperativeKernel((const void*)seq2seq_kernel, dim3(256), dim3(512),
                               args, 0, stream);
}